// Round 4
// baseline (1987.348 us; speedup 1.0000x reference)
//
#include <hip/hip_runtime.h>

#define B_  4096
#define D_  4096
#define H_  2048
#define T_  8
#define M_  6
#define NL  48   // M*T

typedef __attribute__((ext_vector_type(8))) short short8v;
typedef __attribute__((ext_vector_type(4))) short short4v;
typedef __attribute__((ext_vector_type(4))) float float4v;

__device__ __forceinline__ unsigned short f2bf_rne(float f) {
    unsigned u = __float_as_uint(f);
    unsigned r = (u + 0x7fffu + ((u >> 16) & 1u)) >> 16;
    return (unsigned short)r;
}
__device__ __forceinline__ float bf2f(unsigned short h) {
    return __uint_as_float(((unsigned)h) << 16);
}

// ---------------- k_wc: WcT[48][2048] = (W2 @ Ws)^T, bc[48] = b2@Ws + bs ----
__global__ void k_wc(const float* __restrict__ W2, const float* __restrict__ b2,
                     const float* __restrict__ Ws, const float* __restrict__ bs,
                     float* __restrict__ WcT, float* __restrict__ bc) {
    __shared__ float rowl[H_];
    __shared__ float part[4][NL];
    int i = blockIdx.x;
    int tid = threadIdx.x;
    const float* row = (i < H_) ? (W2 + (size_t)i * H_) : b2;
    const float4* r4 = (const float4*)row;
    float4* l4 = (float4*)rowl;
    for (int it = 0; it < 2; ++it) {
        int q = tid + it * 256;
        l4[q] = r4[q];
    }
    __syncthreads();
    if (tid < 192) {
        int n = tid % NL, p = tid / NL;
        float a = 0.f;
        int k0 = p * 512;
        for (int k = k0; k < k0 + 512; ++k)
            a = fmaf(rowl[k], Ws[(size_t)k * NL + n], a);
        part[p][n] = a;
    }
    __syncthreads();
    if (tid < NL) {
        float v = part[0][tid] + part[1][tid] + part[2][tid] + part[3][tid];
        if (i < H_) WcT[(size_t)tid * H_ + i] = v;
        else        bc[tid] = v + bs[tid];
    }
}

// ---------------- k_gemm1: h = relu(x @ W1 + b1), f32 vector GEMM (PRIMARY) -
__global__ __launch_bounds__(256) void k_gemm1(const float* __restrict__ A,
     const float* __restrict__ Bm, const float* __restrict__ b1,
     float* __restrict__ hOut) {
    __shared__ float As[16][132];
    __shared__ float Bs[16][64];
    int tid = threadIdx.x;
    int tx = tid & 15;
    int ty = tid >> 4;
    int m0 = blockIdx.y * 128;
    int n0 = blockIdx.x * 64;
    float acc[8][4] = {};
    int arow = tid >> 1;
    int akv0 = (tid & 1) * 2;
    int bk = tid >> 4;
    int bn = (tid & 15) * 4;
    for (int kb = 0; kb < D_; kb += 16) {
        #pragma unroll
        for (int qq = 0; qq < 2; ++qq) {
            int kv = akv0 + qq;
            float4 v = *(const float4*)(A + (size_t)(m0 + arow) * D_ + kb + kv * 4);
            As[kv*4+0][arow] = v.x;
            As[kv*4+1][arow] = v.y;
            As[kv*4+2][arow] = v.z;
            As[kv*4+3][arow] = v.w;
        }
        {
            float4 v = *(const float4*)(Bm + (size_t)(kb + bk) * H_ + n0 + bn);
            *(float4*)&Bs[bk][bn] = v;
        }
        __syncthreads();
        #pragma unroll
        for (int k = 0; k < 16; ++k) {
            float4 a0 = *(float4*)&As[k][ty*8];
            float4 a1 = *(float4*)&As[k][ty*8+4];
            float4 bq = *(float4*)&Bs[k][tx*4];
            float av[8] = {a0.x,a0.y,a0.z,a0.w,a1.x,a1.y,a1.z,a1.w};
            float bv[4] = {bq.x,bq.y,bq.z,bq.w};
            #pragma unroll
            for (int i = 0; i < 8; ++i)
                #pragma unroll
                for (int j = 0; j < 4; ++j)
                    acc[i][j] = fmaf(av[i], bv[j], acc[i][j]);
        }
        __syncthreads();
    }
    float4 bb = *(const float4*)(b1 + n0 + tx*4);
    float bv[4] = {bb.x, bb.y, bb.z, bb.w};
    #pragma unroll
    for (int i = 0; i < 8; ++i) {
        float4 o;
        o.x = fmaxf(acc[i][0] + bv[0], 0.f);
        o.y = fmaxf(acc[i][1] + bv[1], 0.f);
        o.z = fmaxf(acc[i][2] + bv[2], 0.f);
        o.w = fmaxf(acc[i][3] + bv[3], 0.f);
        *(float4*)(hOut + (size_t)(m0 + ty*8 + i) * H_ + n0 + tx*4) = o;
    }
}

// ---------------- k_logits: logits = h @ Wc + bc; argmax; symbolic chain ----
__global__ void k_logits(const float* __restrict__ h, const float* __restrict__ WcT,
                         const float* __restrict__ bc,
                         const float* __restrict__ adds, const float* __restrict__ subs,
                         const float* __restrict__ muls, const float* __restrict__ divs,
                         float* __restrict__ outLogits, float4* __restrict__ chain) {
    __shared__ float hrow[H_];
    __shared__ float lgt[NL];
    int b = blockIdx.x, tid = threadIdx.x;
    int wave = tid >> 6, lane = tid & 63;
    const float4* h4 = (const float4*)(h + (size_t)b * H_);
    float4* l4 = (float4*)hrow;
    for (int it = 0; it < 2; ++it) l4[tid + it*256] = h4[tid + it*256];
    __syncthreads();
    float acc[12];
    #pragma unroll
    for (int r = 0; r < 12; ++r) acc[r] = 0.f;
    for (int it = 0; it < 32; ++it) {
        int k = it * 64 + lane;
        float hv = hrow[k];
        #pragma unroll
        for (int r = 0; r < 12; ++r)
            acc[r] = fmaf(hv, WcT[(size_t)(wave*12 + r) * H_ + k], acc[r]);
    }
    #pragma unroll
    for (int r = 0; r < 12; ++r) {
        float v = acc[r];
        for (int m = 1; m < 64; m <<= 1) v += __shfl_xor(v, m, 64);
        if (lane == 0) lgt[wave*12 + r] = v;
    }
    __syncthreads();
    if (tid < NL) {
        float v = lgt[tid] + bc[tid];
        lgt[tid] = v;
        outLogits[(size_t)b * NL + tid] = v;
    }
    __syncthreads();
    if (tid == 0) {
        float al = 1.f, be = 0.f;
        int mode = 0;
        float av = adds[0], sv = subs[0], mv = muls[0], dv = divs[0] + 1e-5f;
        for (int t = 0; t < T_; ++t) {
            const float* lr = &lgt[t * M_];
            int best = 0; float bvv = lr[0];
            for (int m = 1; m < M_; ++m) if (lr[m] > bvv) { bvv = lr[m]; best = m; }
            switch (best) {
                case 0: mode = (al >= 0.f) ? 2 : 3; break;
                case 1: mode ^= 1; break;
                case 2: be += av; break;
                case 3: be -= sv; break;
                case 4: al *= mv; be *= mv; break;
                case 5: al /= dv; be /= dv; break;
            }
            chain[(size_t)b * T_ + t] = make_float4(al, be, (float)mode, 0.f);
        }
    }
}

// ---------------- k_out: per-row chain materialization (one sort max) -------
__global__ __launch_bounds__(512) void k_out(const float* __restrict__ x,
    const float4* __restrict__ chain, float* __restrict__ out) {
    __shared__ float xs[D_];
    __shared__ float4 ch[T_];
    int b = blockIdx.x, tid = threadIdx.x;
    const float4* x4 = (const float4*)(x + (size_t)b * D_);
    float4* s4 = (float4*)xs;
    for (int it = 0; it < 2; ++it) s4[tid + it*512] = x4[tid + it*512];
    if (tid < T_) ch[tid] = chain[(size_t)b * T_ + tid];
    __syncthreads();
    bool sorted = false;
    for (int t = 0; t < T_; ++t) {
        float4 c = ch[t];
        int mode = (int)c.z;
        if (mode >= 2 && !sorted) {
            for (int k = 2; k <= D_; k <<= 1) {
                for (int j = k >> 1; j > 0; j >>= 1) {
                    __syncthreads();
                    for (int p = tid; p < D_/2; p += 512) {
                        int i  = ((p & ~(j - 1)) << 1) | (p & (j - 1));
                        int l  = i | j;
                        bool up = (i & k) == 0;
                        float a = xs[i], bb = xs[l];
                        if ((a > bb) == up) { xs[i] = bb; xs[l] = a; }
                    }
                }
            }
            __syncthreads();
            sorted = true;
        }
        float al = c.x, be = c.y;
        bool rev = mode & 1;
        float4* o4 = (float4*)(out + ((size_t)b * T_ + t) * D_);
        for (int it = 0; it < 2; ++it) {
            int q = it * 512 + tid;
            int sq = rev ? (1023 - q) : q;
            float4 v = s4[sq];
            if (rev) { float tm = v.x; v.x = v.w; v.w = tm; tm = v.y; v.y = v.z; v.z = tm; }
            float4 o;
            o.x = fmaf(al, v.x, be);
            o.y = fmaf(al, v.y, be);
            o.z = fmaf(al, v.z, be);
            o.w = fmaf(al, v.w, be);
            o4[q] = o;
        }
    }
}

// ============ SHADOW KERNELS (outputs unused; profiled for timing only) =====

// Split x -> Xh, Xl (bf16 hi + residual-lo), row-major [4096][4096]
__global__ __launch_bounds__(256) void k_split_x(const float* __restrict__ x,
    unsigned short* __restrict__ Xh, unsigned short* __restrict__ Xl) {
    size_t i8 = ((size_t)blockIdx.x * 256 + threadIdx.x) * 8;
    float4 v0 = *(const float4*)(x + i8);
    float4 v1 = *(const float4*)(x + i8 + 4);
    float f[8] = {v0.x,v0.y,v0.z,v0.w,v1.x,v1.y,v1.z,v1.w};
    short8v hi, lo;
    #pragma unroll
    for (int j = 0; j < 8; ++j) {
        unsigned short hb = f2bf_rne(f[j]);
        float r = f[j] - bf2f(hb);
        hi[j] = (short)hb;
        lo[j] = (short)f2bf_rne(r);
    }
    *(short8v*)(Xh + i8) = hi;
    *(short8v*)(Xl + i8) = lo;
}

// Split + transpose W1[4096 k][2048 n] -> Wh/Wl [2048 n][4096 k] bf16
__global__ __launch_bounds__(256) void k_split_w(const float* __restrict__ W1,
    unsigned short* __restrict__ Wh, unsigned short* __restrict__ Wl) {
    __shared__ float t[64][65];
    int tid = threadIdx.x;
    int tx = tid & 15, ty = tid >> 4;
    int n0 = blockIdx.x * 64;   // 0..2047
    int k0 = blockIdx.y * 64;   // 0..4095
    #pragma unroll
    for (int i = 0; i < 4; ++i) {
        int r = ty + i * 16;    // k-offset
        float4 v = *(const float4*)(W1 + (size_t)(k0 + r) * H_ + n0 + tx * 4);
        t[r][tx*4+0] = v.x; t[r][tx*4+1] = v.y; t[r][tx*4+2] = v.z; t[r][tx*4+3] = v.w;
    }
    __syncthreads();
    #pragma unroll
    for (int i = 0; i < 4; ++i) {
        int rT = ty + i * 16;   // n-offset
        short4v hi, lo;
        #pragma unroll
        for (int j = 0; j < 4; ++j) {
            float f = t[tx*4+j][rT];   // W1[k0+tx*4+j][n0+rT]
            unsigned short hb = f2bf_rne(f);
            float r = f - bf2f(hb);
            hi[j] = (short)hb;
            lo[j] = (short)f2bf_rne(r);
        }
        size_t o = (size_t)(n0 + rT) * D_ + k0 + tx * 4;
        *(short4v*)(Wh + o) = hi;
        *(short4v*)(Wl + o) = lo;
    }
}

// 2-split bf16 MFMA GEMM: h = relu((Xh+Xl)@(Wh+Wl)^T + b1), dropping lo*lo.
// 128x128 tile, BK=32, 4 waves (2x2 of 64x64), XOR-swizzled LDS, dbuf,
// 1 barrier/iter, issue-early/write-late staging. 48 MFMA / 16 ds_read_b128 per iter.
__global__ __launch_bounds__(256, 2) void k_gemm_mfma(
    const unsigned short* __restrict__ Xh, const unsigned short* __restrict__ Xl,
    const unsigned short* __restrict__ Wh, const unsigned short* __restrict__ Wl,
    const float* __restrict__ b1, float* __restrict__ hOut) {
    __shared__ char lds[65536];  // buf(32KB) x2: [Ah 8K | Al 8K | Bh 8K | Bl 8K]
    int tid = threadIdx.x;
    int lane = tid & 63, wid = tid >> 6;
    int wm = wid >> 1, wn = wid & 1;
    int m0 = blockIdx.y * 128, n0 = blockIdx.x * 128;
    int l15 = lane & 15, k8 = lane >> 4;

    float4v acc[4][4];
    float4v z = {0.f, 0.f, 0.f, 0.f};
    #pragma unroll
    for (int a = 0; a < 4; ++a)
        #pragma unroll
        for (int b = 0; b < 4; ++b) acc[a][b] = z;

    // staging: 512 chunks of 8 bf16 per (array, K-iter); thread owns chunks tid, tid+256
    int r0 = tid >> 2, s0 = tid & 3;
    int r1 = (tid + 256) >> 2, s1 = tid & 3;  // (tid+256)&3 == tid&3
    // LDS byte offset with XOR swizzle: row*64 + ((slot ^ (row&3))<<4)
    int w0 = r0*64 + (((s0 ^ (r0&3))) << 4);
    int w1 = r1*64 + (((s1 ^ (r1&3))) << 4);
    size_t gA0 = (size_t)(m0 + r0) * D_ + s0 * 8;
    size_t gA1 = (size_t)(m0 + r1) * D_ + s1 * 8;
    size_t gB0 = (size_t)(n0 + r0) * D_ + s0 * 8;
    size_t gB1 = (size_t)(n0 + r1) * D_ + s1 * 8;

    // prologue: stage kb=0 into buf0
    {
        char* nb = lds;
        *(short8v*)(nb + w0)         = *(const short8v*)(Xh + gA0);
        *(short8v*)(nb + w1)         = *(const short8v*)(Xh + gA1);
        *(short8v*)(nb + 8192 + w0)  = *(const short8v*)(Xl + gA0);
        *(short8v*)(nb + 8192 + w1)  = *(const short8v*)(Xl + gA1);
        *(short8v*)(nb + 16384 + w0) = *(const short8v*)(Wh + gB0);
        *(short8v*)(nb + 16384 + w1) = *(const short8v*)(Wh + gB1);
        *(short8v*)(nb + 24576 + w0) = *(const short8v*)(Wl + gB0);
        *(short8v*)(nb + 24576 + w1) = *(const short8v*)(Wl + gB1);
    }
    __syncthreads();

    // per-lane frag read offsets (within an 8KB array region)
    int offA[4], offB[4];
    #pragma unroll
    for (int f = 0; f < 4; ++f) {
        int m = wm*64 + f*16 + l15;
        offA[f] = m*64 + ((k8 ^ (m&3)) << 4);
        int n = wn*64 + f*16 + l15;
        offB[f] = n*64 + ((k8 ^ (n&3)) << 4);
    }

    int cur = 0;
    for (int it = 0; it < D_/32; ++it) {
        short8v p0, p1, p2, p3, p4, p5, p6, p7;
        bool pre = (it < D_/32 - 1);
        if (pre) {
            size_t kn = (size_t)(it + 1) * 32;
            p0 = *(const short8v*)(Xh + gA0 + kn);
            p1 = *(const short8v*)(Xh + gA1 + kn);
            p2 = *(const short8v*)(Xl + gA0 + kn);
            p3 = *(const short8v*)(Xl + gA1 + kn);
            p4 = *(const short8v*)(Wh + gB0 + kn);
            p5 = *(const short8v*)(Wh + gB1 + kn);
            p6 = *(const short8v*)(Wl + gB0 + kn);
            p7 = *(const short8v*)(Wl + gB1 + kn);
        }
        char* buf = lds + cur * 32768;
        short8v ah[4], al[4];
        #pragma unroll
        for (int f = 0; f < 4; ++f) {
            ah[f] = *(const short8v*)(buf + offA[f]);
            al[f] = *(const short8v*)(buf + 8192 + offA[f]);
        }
        #pragma unroll
        for (int nf = 0; nf < 4; ++nf) {
            short8v bh = *(const short8v*)(buf + 16384 + offB[nf]);
            short8v bl = *(const short8v*)(buf + 24576 + offB[nf]);
            #pragma unroll
            for (int mf = 0; mf < 4; ++mf) {
                acc[mf][nf] = __builtin_amdgcn_mfma_f32_16x16x32_bf16(ah[mf], bh, acc[mf][nf], 0, 0, 0);
                acc[mf][nf] = __builtin_amdgcn_mfma_f32_16x16x32_bf16(ah[mf], bl, acc[mf][nf], 0, 0, 0);
                acc[mf][nf] = __builtin_amdgcn_mfma_f32_16x16x32_bf16(al[mf], bh, acc[mf][nf], 0, 0, 0);
            }
        }
        if (pre) {
            char* nb = lds + (cur ^ 1) * 32768;
            *(short8v*)(nb + w0)         = p0;
            *(short8v*)(nb + w1)         = p1;
            *(short8v*)(nb + 8192 + w0)  = p2;
            *(short8v*)(nb + 8192 + w1)  = p3;
            *(short8v*)(nb + 16384 + w0) = p4;
            *(short8v*)(nb + 16384 + w1) = p5;
            *(short8v*)(nb + 24576 + w0) = p6;
            *(short8v*)(nb + 24576 + w1) = p7;
        }
        __syncthreads();
        cur ^= 1;
    }
    #pragma unroll
    for (int mf = 0; mf < 4; ++mf)
        #pragma unroll
        for (int nf = 0; nf < 4; ++nf) {
            int col = n0 + wn*64 + nf*16 + l15;
            float bv = b1[col];
            #pragma unroll
            for (int j = 0; j < 4; ++j) {
                int row = m0 + wm*64 + mf*16 + k8*4 + j;
                hOut[(size_t)row * H_ + col] = fmaxf(acc[mf][nf][j] + bv, 0.f);
            }
        }
}

extern "C" void kernel_launch(void* const* d_in, const int* in_sizes, int n_in,
                              void* d_out, int out_size, void* d_ws, size_t ws_size,
                              hipStream_t stream) {
    const float* x    = (const float*)d_in[0];
    const float* W1   = (const float*)d_in[1];
    const float* b1   = (const float*)d_in[2];
    const float* W2   = (const float*)d_in[3];
    const float* b2   = (const float*)d_in[4];
    const float* Ws   = (const float*)d_in[5];
    const float* bs   = (const float*)d_in[6];
    const float* adds = (const float*)d_in[7];
    const float* subs = (const float*)d_in[8];
    const float* muls = (const float*)d_in[9];
    const float* divs = (const float*)d_in[10];
    float* out = (float*)d_out;

    const size_t MB = 1u << 20;
    const size_t H_BYTES = (size_t)B_ * H_ * sizeof(float);     // 32MB
    char* wsb = (char*)d_ws;

    float4* chain = (float4*)wsb;                  // always at ws+0 (512KB)
    float *WcT, *bc, *hbuf;
    bool shadows = false;
    unsigned short *Xh = nullptr, *Xl = nullptr, *Whh = nullptr, *Wll = nullptr;
    float* hshadow = nullptr;

    if (ws_size >= 168 * MB) {
        WcT = (float*)(wsb + 1*MB); bc = (float*)(wsb + 2*MB);
        hbuf = (float*)(wsb + 4*MB);
        Xh  = (unsigned short*)(wsb + 36*MB);
        Xl  = (unsigned short*)(wsb + 68*MB);
        Whh = (unsigned short*)(wsb + 100*MB);
        Wll = (unsigned short*)(wsb + 116*MB);
        hshadow = (float*)(wsb + 132*MB);
        shadows = true;
    } else if (ws_size >= 36 * MB) {
        WcT = (float*)(wsb + 1*MB); bc = (float*)(wsb + 2*MB);
        hbuf = (float*)(wsb + 4*MB);
    } else {
        // stage in d_out's outputs region; consumed before k_out overwrites it
        char* ob = (char*)d_out;
        hbuf = (float*)ob;
        WcT  = (float*)(ob + H_BYTES);
        bc   = (float*)(ob + H_BYTES + 384u*1024u);
    }
    float* outLogits = out + (size_t)B_ * T_ * D_;

    hipLaunchKernelGGL(k_wc,     dim3(H_ + 1),        dim3(256), 0, stream,
                       W2, b2, Ws, bs, WcT, bc);
    hipLaunchKernelGGL(k_gemm1,  dim3(H_/64, B_/128), dim3(256), 0, stream,
                       x, W1, b1, hbuf);
    hipLaunchKernelGGL(k_logits, dim3(B_),            dim3(256), 0, stream,
                       hbuf, WcT, bc, adds, subs, muls, divs, outLogits, chain);
    hipLaunchKernelGGL(k_out,    dim3(B_),            dim3(512), 0, stream,
                       x, chain, out);

    if (shadows) {  // dead-output experiments, profiled only
        hipLaunchKernelGGL(k_split_x, dim3((B_*(size_t)D_)/(256*8)), dim3(256), 0, stream,
                           x, Xh, Xl);
        hipLaunchKernelGGL(k_split_w, dim3(H_/64, D_/64), dim3(256), 0, stream,
                           W1, Whh, Wll);
        hipLaunchKernelGGL(k_gemm_mfma, dim3(H_/128, B_/128), dim3(256), 0, stream,
                           Xh, Xl, Whh, Wll, b1, hshadow);
    }
}